// Round 2
// baseline (45498.230 us; speedup 1.0000x reference)
//
#include <hip/hip_runtime.h>

#define T 252
#define TPAD 253
#define NLVL 4
#define NOUT 500
#define NSEL 20
#define UBV 0.1f

typedef float v2f __attribute__((ext_vector_type(2)));

#if __has_builtin(__builtin_elementwise_fma)
#define V2FMA(a, b, c) __builtin_elementwise_fma((a), (b), (c))
#else
static __device__ inline v2f V2FMA(v2f a, v2f b, v2f c) {
    v2f r; r.x = fmaf(a.x, b.x, c.x); r.y = fmaf(a.y, b.y, c.y); return r;
}
#endif

// ws layout (floats):
//   [0)        wT1  : conv1 weights [L][i][half][k][c32]   49152
//   [49152)    wT2  : conv2 weights [L][i][half][k][c32]   49152
//   [98304)    awT  : attn_w^T [c][a]                      32000
//   [130304)   fwT  : fc_w^T   [c][a]                      32000
//   [162304)   pooled [B][64]                              131072
#define OFF_WT2    49152
#define OFF_AWT    98304
#define OFF_FWT    130304
#define OFF_POOLED 162304

__global__ __launch_bounds__(256) void transpose_kernel(
    const float* __restrict__ w1, const float* __restrict__ w2,
    const float* __restrict__ aw, const float* __restrict__ fw,
    float* __restrict__ ws)
{
    int idx = blockIdx.x * 256 + threadIdx.x;
    if (idx < 49152) {
        // src: [l][c][i][k]  (l*12288 + c*192 + i*3 + k)
        int l = idx / 12288, r = idx - l * 12288;
        int c = r / 192,     r2 = r - c * 192;
        int i = r2 / 3,      k = r2 - i * 3;
        // dst: [l][i][half][k][c32] — each wave's per-i weights contiguous (96 floats)
        int dst = l * 12288 + i * 192 + (c >> 5) * 96 + k * 32 + (c & 31);
        ws[dst]           = w1[idx];
        ws[OFF_WT2 + dst] = w2[idx];
    }
    if (idx < 32000) {
        int a = idx >> 6, c = idx & 63;   // src [a][c]
        ws[OFF_AWT + c * 500 + a] = aw[idx];
        ws[OFF_FWT + c * 500 + a] = fw[idx];
    }
}

__global__ __launch_bounds__(512, 4) void conv_kernel(
    const float* __restrict__ x,
    const float* __restrict__ ws,
    const float* __restrict__ b1,
    const float* __restrict__ b2,
    float* __restrict__ pooled)
{
    __shared__ float hs[64 * TPAD];   // 64768 B -> 2 blocks/CU

    const int b   = blockIdx.x;
    const int tid = threadIdx.x;          // 0..511
    const int t   = tid & 255;            // timestep slot
    const int chb = (tid >> 8);           // channel half: 0 or 1 (wave-uniform)
    const int ch  = chb * 32;

    // load + transpose x[b] : [T][64] -> hs[f][t]
    const float4* xb = (const float4*)(x + (size_t)b * (T * 64));
    for (int v = tid; v < T * 16; v += 512) {
        float4 val = xb[v];
        int tt = v >> 4, f = (v & 15) << 2;
        hs[(f + 0) * TPAD + tt] = val.x;
        hs[(f + 1) * TPAD + tt] = val.y;
        hs[(f + 2) * TPAD + tt] = val.z;
        hs[(f + 3) * TPAD + tt] = val.w;
    }
    __syncthreads();

    const bool active = (t < T);
    const int  te     = active ? t : (T - 1);

    v2f acc[16], hcol[16];

    for (int lvl = 0; lvl < NLVL; ++lvl) {
        const int d = 1 << lvl;
        const float* W1 = ws + lvl * 12288;
        const float* W2 = ws + OFF_WT2 + lvl * 12288;
        const v2f* B1 = (const v2f*)(b1 + lvl * 64 + ch);
        const v2f* B2 = (const v2f*)(b2 + lvl * 64 + ch);

        // ---- conv1: o1 = relu(W1 * h + b1) ----
        #pragma unroll
        for (int c = 0; c < 16; ++c) acc[c] = B1[c];
        #pragma unroll 4
        for (int i = 0; i < 64; ++i) {
            const float* hr = hs + i * TPAD + te;
            float h2 = hr[0];
            float h1 = (t >= d)     ? hr[-d]     : 0.f;
            float h0 = (t >= 2 * d) ? hr[-2 * d] : 0.f;
            const v2f* Wi = (const v2f*)(W1 + i * 192 + chb * 96); // [k][c32]
            v2f H0 = {h0, h0}, H1 = {h1, h1}, H2 = {h2, h2};
            #pragma unroll
            for (int c = 0; c < 16; ++c) {
                v2f a = acc[c];
                a = V2FMA(Wi[c],      H0, a);
                a = V2FMA(Wi[16 + c], H1, a);
                a = V2FMA(Wi[32 + c], H2, a);
                acc[c] = a;
            }
        }
        // residual column (read BEFORE overwriting h with o1)
        #pragma unroll
        for (int c = 0; c < 16; ++c) {
            hcol[c].x = hs[(ch + 2 * c)     * TPAD + te];
            hcol[c].y = hs[(ch + 2 * c + 1) * TPAD + te];
        }
        __syncthreads();
        if (active) {
            #pragma unroll
            for (int c = 0; c < 16; ++c) {
                hs[(ch + 2 * c)     * TPAD + t] = fmaxf(acc[c].x, 0.f);
                hs[(ch + 2 * c + 1) * TPAD + t] = fmaxf(acc[c].y, 0.f);
            }
        }
        __syncthreads();

        // ---- conv2 + residual: h = relu(relu(W2 * o1 + b2) + h) ----
        #pragma unroll
        for (int c = 0; c < 16; ++c) acc[c] = B2[c];
        #pragma unroll 4
        for (int i = 0; i < 64; ++i) {
            const float* hr = hs + i * TPAD + te;
            float h2 = hr[0];
            float h1 = (t >= d)     ? hr[-d]     : 0.f;
            float h0 = (t >= 2 * d) ? hr[-2 * d] : 0.f;
            const v2f* Wi = (const v2f*)(W2 + i * 192 + chb * 96);
            v2f H0 = {h0, h0}, H1 = {h1, h1}, H2 = {h2, h2};
            #pragma unroll
            for (int c = 0; c < 16; ++c) {
                v2f a = acc[c];
                a = V2FMA(Wi[c],      H0, a);
                a = V2FMA(Wi[16 + c], H1, a);
                a = V2FMA(Wi[32 + c], H2, a);
                acc[c] = a;
            }
        }
        __syncthreads();
        if (active) {
            #pragma unroll
            for (int c = 0; c < 16; ++c) {
                hs[(ch + 2 * c)     * TPAD + t] =
                    fmaxf(fmaxf(acc[c].x, 0.f) + hcol[c].x, 0.f);
                hs[(ch + 2 * c + 1) * TPAD + t] =
                    fmaxf(fmaxf(acc[c].y, 0.f) + hcol[c].y, 0.f);
            }
        }
        __syncthreads();
    }

    // ---- max-pool over time (first 256 threads) ----
    {
        float m = 0.f;
        if (tid < 256) {
            int c = tid & 63, part = tid >> 6;
            const float* row = hs + c * TPAD + part * 63;
            m = row[0];
            for (int j = 1; j < 63; ++j) m = fmaxf(m, row[j]);
        }
        __syncthreads();
        if (tid < 256) hs[tid] = m;
        __syncthreads();
        if (tid < 64) {
            float mm = fmaxf(fmaxf(hs[tid], hs[tid + 64]),
                             fmaxf(hs[tid + 128], hs[tid + 192]));
            pooled[(size_t)b * 64 + tid] = mm;
        }
    }
}

__global__ __launch_bounds__(256) void head_kernel(
    const float* __restrict__ ws,
    const float* __restrict__ proj_w,
    const float* __restrict__ proj_b,
    const float* __restrict__ attn_b,
    const float* __restrict__ fc_b,
    float* __restrict__ out)
{
    const float* awT    = ws + OFF_AWT;
    const float* fwT    = ws + OFF_FWT;
    const float* pooled = ws + OFF_POOLED;

    __shared__ float z[64];
    __shared__ float rs[8];
    __shared__ unsigned long long ks[4];

    const int b   = blockIdx.x;
    const int tid = threadIdx.x;
    const int wv  = tid >> 6, ln = tid & 63;

    // z = relu(pooled @ proj_w^T + proj_b)
    if (tid < 64) {
        float s = proj_b[tid];
        const float* pw = proj_w + tid * 64;
        const float* pl = pooled + (size_t)b * 64;
        #pragma unroll 8
        for (int c = 0; c < 64; ++c) s = fmaf(pw[c], pl[c], s);
        z[tid] = fmaxf(s, 0.f);
    }
    __syncthreads();

    const int a0  = tid;
    const int a1  = tid + 256;
    const int a1e = (a1 < NOUT) ? a1 : (NOUT - 1);

    // attn = sigmoid(z @ attn_w^T + attn_b)
    float l0 = attn_b[a0], l1 = attn_b[a1e];
    #pragma unroll 8
    for (int c = 0; c < 64; ++c) {
        float zc = z[c];
        l0 = fmaf(zc, awT[c * 500 + a0],  l0);
        l1 = fmaf(zc, awT[c * 500 + a1e], l1);
    }
    float v0 = 1.f / (1.f + expf(-l0));
    float v1 = (a1 < NOUT) ? 1.f / (1.f + expf(-l1)) : 0.f;   // sigmoid > 0 for valid

    // top-20 (ties -> lower index, matching lax.top_k)
    bool m0 = false, m1 = false;
    for (int s = 0; s < NSEL; ++s) {
        unsigned long long k0 = ((unsigned long long)__float_as_uint(v0) << 32)
                              | (unsigned)(0xFFFFFFFFu - (unsigned)a0);
        unsigned long long k1 = ((unsigned long long)__float_as_uint(v1) << 32)
                              | (unsigned)(0xFFFFFFFFu - (unsigned)a1);
        unsigned long long k = (k0 > k1) ? k0 : k1;
        for (int o = 32; o > 0; o >>= 1) {
            unsigned long long other = __shfl_xor(k, o);
            if (other > k) k = other;
        }
        if (ln == 0) ks[wv] = k;
        __syncthreads();
        unsigned long long kk = ks[0];
        if (ks[1] > kk) kk = ks[1];
        if (ks[2] > kk) kk = ks[2];
        if (ks[3] > kk) kk = ks[3];
        int wa = (int)(0xFFFFFFFFu - (unsigned)(kk & 0xFFFFFFFFu));
        if (wa == a0) { m0 = true; v0 = 0.f; }
        if (wa == a1) { m1 = true; v1 = 0.f; }
        __syncthreads();
    }

    // fc logits
    float f0 = fc_b[a0], f1 = fc_b[a1e];
    #pragma unroll 8
    for (int c = 0; c < 64; ++c) {
        float zc = z[c];
        f0 = fmaf(zc, fwT[c * 500 + a0],  f0);
        f1 = fmaf(zc, fwT[c * 500 + a1e], f1);
    }
    if (a1 >= NOUT) f1 = -1e30f;

    // softmax over all 500
    float mx = fmaxf(f0, f1);
    for (int o = 32; o > 0; o >>= 1) mx = fmaxf(mx, __shfl_xor(mx, o));
    if (ln == 0) rs[wv] = mx;
    __syncthreads();
    mx = fmaxf(fmaxf(rs[0], rs[1]), fmaxf(rs[2], rs[3]));
    __syncthreads();

    float e0 = expf(f0 - mx);
    float e1 = (a1 < NOUT) ? expf(f1 - mx) : 0.f;
    float sm = e0 + e1;
    for (int o = 32; o > 0; o >>= 1) sm += __shfl_xor(sm, o);
    if (ln == 0) rs[wv] = sm;
    __syncthreads();
    float Z = rs[0] + rs[1] + rs[2] + rs[3];
    __syncthreads();

    float p0 = m0 ? (e0 / Z) : 0.f;
    float p1 = m1 ? (e1 / Z) : 0.f;
    float S = p0 + p1;
    for (int o = 32; o > 0; o >>= 1) S += __shfl_xor(S, o);
    if (ln == 0) rs[wv] = S;
    __syncthreads();
    S = rs[0] + rs[1] + rs[2] + rs[3];
    __syncthreads();

    float w0 = p0 / (S + 1e-8f);
    float w1 = p1 / (S + 1e-8f);

    // water-filling rebalance: 1 + 16 iterations; gated iterations are exact
    // fixed points (leftover == 0.0 -> update adds exactly 0), so run all 17.
    for (int it = 0; it < 17; ++it) {
        float c0 = fminf(fmaxf(w0, 0.f), UBV);
        float c1 = fminf(fmaxf(w1, 0.f), UBV);
        float lo = (w0 - c0) + (w1 - c1);
        float ns = ((c0 != UBV) ? c0 : 0.f) + ((c1 != UBV) ? c1 : 0.f);
        for (int o = 32; o > 0; o >>= 1) {
            lo += __shfl_xor(lo, o);
            ns += __shfl_xor(ns, o);
        }
        if (ln == 0) { rs[wv * 2] = lo; rs[wv * 2 + 1] = ns; }
        __syncthreads();
        lo = rs[0] + rs[2] + rs[4] + rs[6];
        ns = rs[1] + rs[3] + rs[5] + rs[7];
        __syncthreads();
        if (ns == 0.f) ns = 1.f;
        w0 = (c0 != UBV) ? c0 + lo * c0 / ns : c0;
        w1 = (c1 != UBV) ? c1 + lo * c1 / ns : c1;
    }

    out[(size_t)b * 500 + a0] = w0;
    if (a1 < NOUT) out[(size_t)b * 500 + a1] = w1;
}

extern "C" void kernel_launch(void* const* d_in, const int* in_sizes, int n_in,
                              void* d_out, int out_size, void* d_ws, size_t ws_size,
                              hipStream_t stream)
{
    const float* x   = (const float*)d_in[0];
    const float* c1w = (const float*)d_in[1];
    const float* c1b = (const float*)d_in[2];
    const float* c2w = (const float*)d_in[3];
    const float* c2b = (const float*)d_in[4];
    const float* pw  = (const float*)d_in[5];
    const float* pb  = (const float*)d_in[6];
    const float* aw  = (const float*)d_in[7];
    const float* ab  = (const float*)d_in[8];
    const float* fw  = (const float*)d_in[9];
    const float* fb  = (const float*)d_in[10];

    float* ws  = (float*)d_ws;
    float* out = (float*)d_out;

    transpose_kernel<<<192, 256, 0, stream>>>(c1w, c2w, aw, fw, ws);
    conv_kernel<<<2048, 512, 0, stream>>>(x, ws, c1b, c2b, ws + OFF_POOLED);
    head_kernel<<<2048, 256, 0, stream>>>(ws, pw, pb, ab, fb, out);
}

// Round 3
// 1519.566 us; speedup vs baseline: 29.9416x; 29.9416x over previous
//
#include <hip/hip_runtime.h>

#define T 252
#define RSTR 268            // 16 zero left-pad + 252 timesteps; odd-ish bank spread (12 mod 32)
#define LDS_DWORDS (64 * RSTR + 16)   // +16 slack: row-63 window over-read stays in-bounds
#define NOUT 500
#define NSEL 20
#define UBV 0.1f

// ws layout (floats):
//   [0)        wT1 : conv1 weights [lvl][i][c][4]   65536
//   [65536)    wT2 : conv2 weights [lvl][i][c][4]   65536
//   [131072)   awT : attn_w^T [c][a]                32000
//   [163072)   fwT : fc_w^T   [c][a]                32000
//   [195072)   pooled [B][64]                       131072
#define OFF_WT2    65536
#define OFF_AWT    131072
#define OFF_FWT    163072
#define OFF_POOLED 195072

__global__ __launch_bounds__(256) void transpose_kernel(
    const float* __restrict__ w1, const float* __restrict__ w2,
    const float* __restrict__ aw, const float* __restrict__ fw,
    float* __restrict__ ws)
{
    int idx = blockIdx.x * 256 + threadIdx.x;
    if (idx < 49152) {
        // src: [l][cout][cin][k]  (l*12288 + cout*192 + i*3 + k)
        int l = idx / 12288, r = idx - l * 12288;
        int c = r / 192,     r2 = r - c * 192;
        int i = r2 / 3,      k = r2 - i * 3;
        // dst: [l][i][c][4]; k=0 pairs h[t-2d] (reference k order preserved)
        int dst = (((l * 64 + i) * 64 + c) << 2) + k;
        ws[dst]           = w1[idx];
        ws[OFF_WT2 + dst] = w2[idx];
    }
    if (idx < 32000) {
        int a = idx >> 6, c = idx & 63;   // src [a][c]
        ws[OFF_AWT + c * 500 + a] = aw[idx];
        ws[OFF_FWT + c * 500 + a] = fw[idx];
    }
}

extern __shared__ float hs[];

__global__ __launch_bounds__(512, 2) void conv_kernel(
    const float* __restrict__ x,
    const float* __restrict__ ws,
    const float* __restrict__ b1,
    const float* __restrict__ b2,
    float* __restrict__ pooled)
{
    const int b   = blockIdx.x;
    const int tid = threadIdx.x;       // 0..511
    const int c   = tid & 63;          // lane = channel
    const int wv  = tid >> 6;          // wave id 0..7
    const int t0  = wv * 32;           // t-tile [t0, t0+32)

    // zero the 16-col left pad of every row (+ slack tail)
    for (int j = tid; j < 64 * 16 + 16; j += 512) {
        int r = j >> 4, q = j & 15;
        hs[(j < 64 * 16) ? (r * RSTR + q) : (64 * RSTR + (j - 64 * 16))] = 0.f;
    }
    // load + transpose x[b]: [T][64] -> hs[f][16+t]
    const float4* xb = (const float4*)(x + (size_t)b * (T * 64));
    for (int v = tid; v < T * 16; v += 512) {
        float4 val = xb[v];
        int t = v >> 4, f = (v & 15) << 2;
        hs[(f + 0) * RSTR + 16 + t] = val.x;
        hs[(f + 1) * RSTR + 16 + t] = val.y;
        hs[(f + 2) * RSTR + 16 + t] = val.z;
        hs[(f + 3) * RSTR + 16 + t] = val.w;
    }
    __syncthreads();

    float acc[32];
    const float4* W1base = (const float4*)ws;
    const float4* W2base = (const float4*)(ws + OFF_WT2);

    #pragma unroll
    for (int lvl = 0; lvl < 4; ++lvl) {
        const int d = 1 << lvl;
        const float4* Wq1 = W1base + (lvl << 12);
        const float4* Wq2 = W2base + (lvl << 12);
        const float bb1 = b1[(lvl << 6) + c];
        const float bb2 = b2[(lvl << 6) + c];

        // ---- conv1: o1 = relu(W1 * h + b1) ----
        #pragma unroll
        for (int j = 0; j < 32; ++j) acc[j] = bb1;
        {
            float4 wnx = Wq1[c];
            #pragma unroll 1
            for (int i = 0; i < 64; ++i) {
                float4 wv4 = wnx;
                int inx = (i < 63) ? i + 1 : 63;
                wnx = Wq1[(inx << 6) + c];                 // prefetch next i
                const float4* hw = (const float4*)(hs + i * RSTR + t0);
                float4 H[12];
                #pragma unroll
                for (int q = 0; q < 12; ++q) H[q] = hw[q]; // uniform broadcast b128
                const float* Hf = (const float*)H;         // Hf[p] <-> t = t0-16+p
                #pragma unroll
                for (int j = 0; j < 32; ++j) {
                    float a = acc[j];
                    a = fmaf(wv4.x, Hf[j + 16 - 2 * d], a);
                    a = fmaf(wv4.y, Hf[j + 16 - d],     a);
                    a = fmaf(wv4.z, Hf[j + 16],         a);
                    acc[j] = a;
                }
            }
        }
        // residual (own row, read before overwrite)
        float4 R[8];
        {
            const float4* hrow = (const float4*)(hs + c * RSTR + 16 + t0);
            #pragma unroll
            for (int q = 0; q < 8; ++q) R[q] = hrow[q];
        }
        __syncthreads();
        {
            float4* wrow = (float4*)(hs + c * RSTR + 16 + t0);
            #pragma unroll
            for (int q = 0; q < 8; ++q) {
                if (t0 + 4 * q + 3 < T) {
                    float4 o;
                    o.x = fmaxf(acc[4 * q + 0], 0.f);
                    o.y = fmaxf(acc[4 * q + 1], 0.f);
                    o.z = fmaxf(acc[4 * q + 2], 0.f);
                    o.w = fmaxf(acc[4 * q + 3], 0.f);
                    wrow[q] = o;
                }
            }
        }
        __syncthreads();

        // ---- conv2 + residual ----
        #pragma unroll
        for (int j = 0; j < 32; ++j) acc[j] = bb2;
        {
            float4 wnx = Wq2[c];
            #pragma unroll 1
            for (int i = 0; i < 64; ++i) {
                float4 wv4 = wnx;
                int inx = (i < 63) ? i + 1 : 63;
                wnx = Wq2[(inx << 6) + c];
                const float4* hw = (const float4*)(hs + i * RSTR + t0);
                float4 H[12];
                #pragma unroll
                for (int q = 0; q < 12; ++q) H[q] = hw[q];
                const float* Hf = (const float*)H;
                #pragma unroll
                for (int j = 0; j < 32; ++j) {
                    float a = acc[j];
                    a = fmaf(wv4.x, Hf[j + 16 - 2 * d], a);
                    a = fmaf(wv4.y, Hf[j + 16 - d],     a);
                    a = fmaf(wv4.z, Hf[j + 16],         a);
                    acc[j] = a;
                }
            }
        }
        __syncthreads();
        {
            float4* wrow = (float4*)(hs + c * RSTR + 16 + t0);
            #pragma unroll
            for (int q = 0; q < 8; ++q) {
                if (t0 + 4 * q + 3 < T) {
                    float4 o;
                    o.x = fmaxf(fmaxf(acc[4 * q + 0], 0.f) + R[q].x, 0.f);
                    o.y = fmaxf(fmaxf(acc[4 * q + 1], 0.f) + R[q].y, 0.f);
                    o.z = fmaxf(fmaxf(acc[4 * q + 2], 0.f) + R[q].z, 0.f);
                    o.w = fmaxf(fmaxf(acc[4 * q + 3], 0.f) + R[q].w, 0.f);
                    wrow[q] = o;
                }
            }
        }
        __syncthreads();
    }

    // ---- max-pool over time ----
    {
        const int p = wv;                       // 8 parts x 32 t
        const float* row = hs + c * RSTR + 16 + p * 32;
        const int n = (p == 7) ? 28 : 32;
        float m = row[0];
        for (int j = 1; j < n; ++j) m = fmaxf(m, row[j]);
        __syncthreads();
        hs[p * 64 + c] = m;
        __syncthreads();
        if (tid < 64) {
            float mm = hs[tid];
            #pragma unroll
            for (int q = 1; q < 8; ++q) mm = fmaxf(mm, hs[q * 64 + tid]);
            pooled[(size_t)b * 64 + tid] = mm;
        }
    }
}

__global__ __launch_bounds__(256) void head_kernel(
    const float* __restrict__ ws,
    const float* __restrict__ proj_w,
    const float* __restrict__ proj_b,
    const float* __restrict__ attn_b,
    const float* __restrict__ fc_b,
    float* __restrict__ out)
{
    const float* awT    = ws + OFF_AWT;
    const float* fwT    = ws + OFF_FWT;
    const float* pooled = ws + OFF_POOLED;

    __shared__ float z[64];
    __shared__ float rs[8];
    __shared__ unsigned long long ks[4];

    const int b   = blockIdx.x;
    const int tid = threadIdx.x;
    const int wv  = tid >> 6, ln = tid & 63;

    if (tid < 64) {
        float s = proj_b[tid];
        const float* pw = proj_w + tid * 64;
        const float* pl = pooled + (size_t)b * 64;
        #pragma unroll 8
        for (int c = 0; c < 64; ++c) s = fmaf(pw[c], pl[c], s);
        z[tid] = fmaxf(s, 0.f);
    }
    __syncthreads();

    const int a0  = tid;
    const int a1  = tid + 256;
    const int a1e = (a1 < NOUT) ? a1 : (NOUT - 1);

    float l0 = attn_b[a0], l1 = attn_b[a1e];
    #pragma unroll 8
    for (int c = 0; c < 64; ++c) {
        float zc = z[c];
        l0 = fmaf(zc, awT[c * 500 + a0],  l0);
        l1 = fmaf(zc, awT[c * 500 + a1e], l1);
    }
    float v0 = 1.f / (1.f + expf(-l0));
    float v1 = (a1 < NOUT) ? 1.f / (1.f + expf(-l1)) : 0.f;

    bool m0 = false, m1 = false;
    for (int s = 0; s < NSEL; ++s) {
        unsigned long long k0 = ((unsigned long long)__float_as_uint(v0) << 32)
                              | (unsigned)(0xFFFFFFFFu - (unsigned)a0);
        unsigned long long k1 = ((unsigned long long)__float_as_uint(v1) << 32)
                              | (unsigned)(0xFFFFFFFFu - (unsigned)a1);
        unsigned long long k = (k0 > k1) ? k0 : k1;
        for (int o = 32; o > 0; o >>= 1) {
            unsigned long long other = __shfl_xor(k, o);
            if (other > k) k = other;
        }
        if (ln == 0) ks[wv] = k;
        __syncthreads();
        unsigned long long kk = ks[0];
        if (ks[1] > kk) kk = ks[1];
        if (ks[2] > kk) kk = ks[2];
        if (ks[3] > kk) kk = ks[3];
        int wa = (int)(0xFFFFFFFFu - (unsigned)(kk & 0xFFFFFFFFu));
        if (wa == a0) { m0 = true; v0 = 0.f; }
        if (wa == a1) { m1 = true; v1 = 0.f; }
        __syncthreads();
    }

    float f0 = fc_b[a0], f1 = fc_b[a1e];
    #pragma unroll 8
    for (int c = 0; c < 64; ++c) {
        float zc = z[c];
        f0 = fmaf(zc, fwT[c * 500 + a0],  f0);
        f1 = fmaf(zc, fwT[c * 500 + a1e], f1);
    }
    if (a1 >= NOUT) f1 = -1e30f;

    float mx = fmaxf(f0, f1);
    for (int o = 32; o > 0; o >>= 1) mx = fmaxf(mx, __shfl_xor(mx, o));
    if (ln == 0) rs[wv] = mx;
    __syncthreads();
    mx = fmaxf(fmaxf(rs[0], rs[1]), fmaxf(rs[2], rs[3]));
    __syncthreads();

    float e0 = expf(f0 - mx);
    float e1 = (a1 < NOUT) ? expf(f1 - mx) : 0.f;
    float sm = e0 + e1;
    for (int o = 32; o > 0; o >>= 1) sm += __shfl_xor(sm, o);
    if (ln == 0) rs[wv] = sm;
    __syncthreads();
    float Z = rs[0] + rs[1] + rs[2] + rs[3];
    __syncthreads();

    float p0 = m0 ? (e0 / Z) : 0.f;
    float p1 = m1 ? (e1 / Z) : 0.f;
    float S = p0 + p1;
    for (int o = 32; o > 0; o >>= 1) S += __shfl_xor(S, o);
    if (ln == 0) rs[wv] = S;
    __syncthreads();
    S = rs[0] + rs[1] + rs[2] + rs[3];
    __syncthreads();

    float w0 = p0 / (S + 1e-8f);
    float w1 = p1 / (S + 1e-8f);

    for (int it = 0; it < 17; ++it) {
        float c0 = fminf(fmaxf(w0, 0.f), UBV);
        float c1 = fminf(fmaxf(w1, 0.f), UBV);
        float lo = (w0 - c0) + (w1 - c1);
        float ns = ((c0 != UBV) ? c0 : 0.f) + ((c1 != UBV) ? c1 : 0.f);
        for (int o = 32; o > 0; o >>= 1) {
            lo += __shfl_xor(lo, o);
            ns += __shfl_xor(ns, o);
        }
        if (ln == 0) { rs[wv * 2] = lo; rs[wv * 2 + 1] = ns; }
        __syncthreads();
        lo = rs[0] + rs[2] + rs[4] + rs[6];
        ns = rs[1] + rs[3] + rs[5] + rs[7];
        __syncthreads();
        if (ns == 0.f) ns = 1.f;
        w0 = (c0 != UBV) ? c0 + lo * c0 / ns : c0;
        w1 = (c1 != UBV) ? c1 + lo * c1 / ns : c1;
    }

    out[(size_t)b * 500 + a0] = w0;
    if (a1 < NOUT) out[(size_t)b * 500 + a1] = w1;
}

extern "C" void kernel_launch(void* const* d_in, const int* in_sizes, int n_in,
                              void* d_out, int out_size, void* d_ws, size_t ws_size,
                              hipStream_t stream)
{
    const float* x   = (const float*)d_in[0];
    const float* c1w = (const float*)d_in[1];
    const float* c1b = (const float*)d_in[2];
    const float* c2w = (const float*)d_in[3];
    const float* c2b = (const float*)d_in[4];
    const float* pw  = (const float*)d_in[5];
    const float* pb  = (const float*)d_in[6];
    const float* aw  = (const float*)d_in[7];
    const float* ab  = (const float*)d_in[8];
    const float* fw  = (const float*)d_in[9];
    const float* fb  = (const float*)d_in[10];

    float* ws  = (float*)d_ws;
    float* out = (float*)d_out;

    (void)hipFuncSetAttribute((const void*)conv_kernel,
                              hipFuncAttributeMaxDynamicSharedMemorySize,
                              LDS_DWORDS * 4);

    transpose_kernel<<<192, 256, 0, stream>>>(c1w, c2w, aw, fw, ws);
    conv_kernel<<<2048, 512, LDS_DWORDS * 4, stream>>>(x, ws, c1b, c2b, ws + OFF_POOLED);
    head_kernel<<<2048, 256, 0, stream>>>(ws, pw, pb, ab, fb, out);
}

// Round 4
// 615.066 us; speedup vs baseline: 73.9729x; 2.4706x over previous
//
#include <hip/hip_runtime.h>

#define T 252
#define NOUT 500
#define NSEL 20
#define UBV 0.1f

// LDS activation planes: [row = 16 zero-pad + 256 t][col = 64 ch], ushort bf16
#define STR_US 72                     // row stride in ushorts (144 B, 16B-mult)
#define ROWS 272
#define PLANE_US (ROWS * STR_US)      // 19584 ushorts per plane
#define PLANE_U  (PLANE_US / 2)       // 9792 uints per plane
#define LDS_BYTES (2 * PLANE_US * 2)  // 78336 B (hi + lo planes)

// ws layout (floats):
//   [0)        AF : W MFMA A-frags, 384 frags x 256 dwords    98304
//   [98304)    awT : attn_w^T [c][a]                          32000
//   [130304)   fwT : fc_w^T   [c][a]                          32000
//   [162304)   pooled [B][64]                                 131072
#define OFF_AWT    98304
#define OFF_FWT    130304
#define OFF_POOLED 162304

typedef short bf8 __attribute__((ext_vector_type(8)));   // 8 bf16 = 4 VGPR
typedef float f32x4 __attribute__((ext_vector_type(4)));

static __device__ __forceinline__ unsigned short f2bf(float f) {
    unsigned u = __float_as_uint(f);
    return (unsigned short)((u + 0x7fffu + ((u >> 16) & 1u)) >> 16);   // RNE
}
static __device__ __forceinline__ float bf2f(unsigned short h) {
    return __uint_as_float(((unsigned)h) << 16);
}

// ---------- prep: pack W into A-fragments + head transposes ----------
// fragid = ((((buf*4+lvl)*2+Kt)*3+tap)*4+m)*2+s ; per frag: [lane][4 dwords]
// A-frag lane map (16x16x32 bf16): c = m*16 + (lane&15), i = Kt*32 + (lane>>4)*8 + j
__global__ __launch_bounds__(256) void prep_kernel(
    const float* __restrict__ w1, const float* __restrict__ w2,
    const float* __restrict__ aw, const float* __restrict__ fw,
    float* __restrict__ ws)
{
    int gid = blockIdx.x * 256 + threadIdx.x;
    if (gid < 24576) {
        int frag = gid >> 6, lane = gid & 63;
        int s   = frag & 1;
        int m   = (frag >> 1) & 3;
        int t3  = frag >> 3;
        int tap = t3 % 3;
        int q   = t3 / 3;
        int Kt  = q & 1;
        int lvl = (q >> 1) & 3;
        int buf = q >> 3;
        int c  = m * 16 + (lane & 15);
        int i0 = Kt * 32 + (lane >> 4) * 8;
        const float* W = (buf ? w2 : w1) + lvl * 12288 + c * 192;
        unsigned short v[8];
        for (int j = 0; j < 8; ++j) {
            float x = W[(i0 + j) * 3 + tap];
            unsigned short hi = f2bf(x);
            if (s == 0) v[j] = hi;
            else        v[j] = f2bf(x - bf2f(hi));
        }
        unsigned* dst = (unsigned*)ws + frag * 256 + lane * 4;
        for (int d = 0; d < 4; ++d)
            dst[d] = (unsigned)v[2 * d] | ((unsigned)v[2 * d + 1] << 16);
    }
    if (gid < 32000) {
        int a = gid >> 6, c = gid & 63;   // src [a][c]
        ws[OFF_AWT + c * 500 + a] = aw[gid];
        ws[OFF_FWT + c * 500 + a] = fw[gid];
    }
}

extern __shared__ unsigned short lds[];

#define MFMA(A, B, C) __builtin_amdgcn_mfma_f32_16x16x32_bf16((A), (B), (C), 0, 0, 0)

__global__ __launch_bounds__(256, 2) void conv_kernel(
    const float* __restrict__ x,
    const float* __restrict__ ws,
    const float* __restrict__ b1,
    const float* __restrict__ b2,
    float* __restrict__ pooled)
{
    const int b    = blockIdx.x;
    const int tid  = threadIdx.x;
    const int lane = tid & 63;
    const int wv   = tid >> 6;            // 4 waves; wave handles ntiles 4wv..4wv+3

    unsigned* Lh = (unsigned*)lds;
    unsigned* Ll = Lh + PLANE_U;

    // zero pad rows 0..15 (t<0) and 268..271 (t>=252), both planes
    for (int j = tid; j < 720; j += 256) {
        int r20 = j / 36, col = j % 36;
        int r = (r20 < 16) ? r20 : (252 + r20);
        Lh[r * 36 + col] = 0u;
        Ll[r * 36 + col] = 0u;
    }
    // ingest x[b]: [252][64] fp32 -> split hi/lo bf16 planes (layout matches!)
    const float4* xb = (const float4*)(x + (size_t)b * (T * 64));
    for (int v = tid; v < T * 16; v += 256) {
        float4 xv = xb[v];
        int t = v >> 4, i4 = (v & 15) << 2;
        float vv[4] = {xv.x, xv.y, xv.z, xv.w};
        unsigned short h_[4], l_[4];
        #pragma unroll
        for (int r = 0; r < 4; ++r) {
            h_[r] = f2bf(vv[r]);
            l_[r] = f2bf(vv[r] - bf2f(h_[r]));
        }
        int base = (16 + t) * 36 + (i4 >> 1);
        Lh[base]     = (unsigned)h_[0] | ((unsigned)h_[1] << 16);
        Lh[base + 1] = (unsigned)h_[2] | ((unsigned)h_[3] << 16);
        Ll[base]     = (unsigned)l_[0] | ((unsigned)l_[1] << 16);
        Ll[base + 1] = (unsigned)l_[2] | ((unsigned)l_[3] << 16);
    }
    __syncthreads();

    const uint4* AF4 = (const uint4*)ws;
    const int g4 = (lane >> 4) << 2;          // 4*(lane/16)
    const int ln16 = lane & 15;

    uint2 hh[4][4], hl[4][4];                 // saved h_old at D-tile (hi/lo packed)

    for (int lvl = 0; lvl < 4; ++lvl) {
        const int d = 1 << lvl;
        for (int cv = 0; cv < 2; ++cv) {
            f32x4 acc[4][4];
            #pragma unroll
            for (int m = 0; m < 4; ++m)
                #pragma unroll
                for (int nn = 0; nn < 4; ++nn)
                    acc[m][nn] = (f32x4){0.f, 0.f, 0.f, 0.f};

            #pragma unroll
            for (int Kt = 0; Kt < 2; ++Kt) {
                #pragma unroll
                for (int tap = 0; tap < 3; ++tap) {
                    const int shift = (2 - tap) * d;
                    const int fb = (((cv * 4 + lvl) * 2 + Kt) * 3 + tap) * 8;
                    bf8 Ah[4], Al[4];
                    #pragma unroll
                    for (int m = 0; m < 4; ++m) {
                        uint4 ta = AF4[(fb + 2 * m) * 64 + lane];
                        uint4 tb = AF4[(fb + 2 * m + 1) * 64 + lane];
                        Ah[m] = *(bf8*)&ta;
                        Al[m] = *(bf8*)&tb;
                    }
                    bf8 Bh[4], Bl[4];
                    #pragma unroll
                    for (int nn = 0; nn < 4; ++nn) {
                        int row = 16 + (4 * wv + nn) * 16 + ln16 - shift;
                        int ui  = row * 36 + Kt * 16 + g4;
                        Bh[nn] = *(const bf8*)(Lh + ui);
                        Bl[nn] = *(const bf8*)(Ll + ui);
                    }
                    #pragma unroll
                    for (int m = 0; m < 4; ++m)
                        #pragma unroll
                        for (int nn = 0; nn < 4; ++nn) {
                            f32x4 a = acc[m][nn];
                            a = MFMA(Ah[m], Bh[nn], a);
                            a = MFMA(Ah[m], Bl[nn], a);
                            a = MFMA(Al[m], Bh[nn], a);
                            a = MFMA(Al[m], Bl[nn], a);
                            acc[m][nn] = a;
                        }
                }
            }

            // epilogue: D map: t = ntile*16 + (lane&15), c = m*16 + 4*(lane>>4) + reg
            if (cv == 0) {
                // save h_old at this wave's D-tile before overwriting with o1
                #pragma unroll
                for (int m = 0; m < 4; ++m)
                    #pragma unroll
                    for (int nn = 0; nn < 4; ++nn) {
                        int row = 16 + (4 * wv + nn) * 16 + ln16;
                        int ui  = row * 36 + ((m * 16 + g4) >> 1);
                        hh[m][nn] = *(uint2*)(Lh + ui);
                        hl[m][nn] = *(uint2*)(Ll + ui);
                    }
                __syncthreads();   // all reads of h_old done
                #pragma unroll
                for (int m = 0; m < 4; ++m) {
                    int c0 = m * 16 + g4;
                    float4 bv = *(const float4*)(b1 + lvl * 64 + c0);
                    float bb[4] = {bv.x, bv.y, bv.z, bv.w};
                    #pragma unroll
                    for (int nn = 0; nn < 4; ++nn) {
                        int row = 16 + (4 * wv + nn) * 16 + ln16;
                        int ui  = row * 36 + (c0 >> 1);
                        unsigned short h_[4], l_[4];
                        #pragma unroll
                        for (int r = 0; r < 4; ++r) {
                            float o = fmaxf(acc[m][nn][r] + bb[r], 0.f);
                            h_[r] = f2bf(o);
                            l_[r] = f2bf(o - bf2f(h_[r]));
                        }
                        uint2 wh, wl;
                        wh.x = (unsigned)h_[0] | ((unsigned)h_[1] << 16);
                        wh.y = (unsigned)h_[2] | ((unsigned)h_[3] << 16);
                        wl.x = (unsigned)l_[0] | ((unsigned)l_[1] << 16);
                        wl.y = (unsigned)l_[2] | ((unsigned)l_[3] << 16);
                        *(uint2*)(Lh + ui) = wh;
                        *(uint2*)(Ll + ui) = wl;
                    }
                }
                __syncthreads();   // o1 visible
            } else {
                __syncthreads();   // all reads of o1 done
                #pragma unroll
                for (int m = 0; m < 4; ++m) {
                    int c0 = m * 16 + g4;
                    float4 bv = *(const float4*)(b2 + lvl * 64 + c0);
                    float bb[4] = {bv.x, bv.y, bv.z, bv.w};
                    #pragma unroll
                    for (int nn = 0; nn < 4; ++nn) {
                        int row = 16 + (4 * wv + nn) * 16 + ln16;
                        int ui  = row * 36 + (c0 >> 1);
                        unsigned hx = hh[m][nn].x, hy = hh[m][nn].y;
                        unsigned lx = hl[m][nn].x, ly = hl[m][nn].y;
                        float hold[4] = {
                            bf2f((unsigned short)(hx & 0xffff)) + bf2f((unsigned short)(lx & 0xffff)),
                            bf2f((unsigned short)(hx >> 16))    + bf2f((unsigned short)(lx >> 16)),
                            bf2f((unsigned short)(hy & 0xffff)) + bf2f((unsigned short)(ly & 0xffff)),
                            bf2f((unsigned short)(hy >> 16))    + bf2f((unsigned short)(ly >> 16))};
                        unsigned short h_[4], l_[4];
                        #pragma unroll
                        for (int r = 0; r < 4; ++r) {
                            float o = fmaxf(acc[m][nn][r] + bb[r], 0.f);
                            float hn = fmaxf(o + hold[r], 0.f);
                            h_[r] = f2bf(hn);
                            l_[r] = f2bf(hn - bf2f(h_[r]));
                        }
                        uint2 wh, wl;
                        wh.x = (unsigned)h_[0] | ((unsigned)h_[1] << 16);
                        wh.y = (unsigned)h_[2] | ((unsigned)h_[3] << 16);
                        wl.x = (unsigned)l_[0] | ((unsigned)l_[1] << 16);
                        wl.y = (unsigned)l_[2] | ((unsigned)l_[3] << 16);
                        *(uint2*)(Lh + ui) = wh;
                        *(uint2*)(Ll + ui) = wl;
                    }
                }
                __syncthreads();   // h_new visible
            }
        }
    }

    // ---- max-pool over t (values >= 0 after relu) ----
    {
        int c = tid & 63, part = tid >> 6;     // 4 parts x 63 t = 252
        float mx = 0.f;
        for (int j = 0; j < 63; ++j) {
            int row = 16 + part * 63 + j;
            unsigned short vh = lds[row * STR_US + c];
            unsigned short vl = lds[PLANE_US + row * STR_US + c];
            mx = fmaxf(mx, bf2f(vh) + bf2f(vl));
        }
        __syncthreads();
        ((float*)lds)[tid] = mx;
        __syncthreads();
        if (tid < 64) {
            float* fs = (float*)lds;
            float mm = fmaxf(fmaxf(fs[tid], fs[tid + 64]),
                             fmaxf(fs[tid + 128], fs[tid + 192]));
            pooled[(size_t)b * 64 + tid] = mm;
        }
    }
}

__global__ __launch_bounds__(256) void head_kernel(
    const float* __restrict__ ws,
    const float* __restrict__ proj_w,
    const float* __restrict__ proj_b,
    const float* __restrict__ attn_b,
    const float* __restrict__ fc_b,
    float* __restrict__ out)
{
    const float* awT    = ws + OFF_AWT;
    const float* fwT    = ws + OFF_FWT;
    const float* pooled = ws + OFF_POOLED;

    __shared__ float z[64];
    __shared__ float rs[8];
    __shared__ unsigned long long ks[4];

    const int b   = blockIdx.x;
    const int tid = threadIdx.x;
    const int wv  = tid >> 6, ln = tid & 63;

    if (tid < 64) {
        float s = proj_b[tid];
        const float* pw = proj_w + tid * 64;
        const float* pl = pooled + (size_t)b * 64;
        #pragma unroll 8
        for (int c = 0; c < 64; ++c) s = fmaf(pw[c], pl[c], s);
        z[tid] = fmaxf(s, 0.f);
    }
    __syncthreads();

    const int a0  = tid;
    const int a1  = tid + 256;
    const int a1e = (a1 < NOUT) ? a1 : (NOUT - 1);

    float l0 = attn_b[a0], l1 = attn_b[a1e];
    #pragma unroll 8
    for (int c = 0; c < 64; ++c) {
        float zc = z[c];
        l0 = fmaf(zc, awT[c * 500 + a0],  l0);
        l1 = fmaf(zc, awT[c * 500 + a1e], l1);
    }
    float v0 = 1.f / (1.f + expf(-l0));
    float v1 = (a1 < NOUT) ? 1.f / (1.f + expf(-l1)) : 0.f;

    bool m0 = false, m1 = false;
    for (int s = 0; s < NSEL; ++s) {
        unsigned long long k0 = ((unsigned long long)__float_as_uint(v0) << 32)
                              | (unsigned)(0xFFFFFFFFu - (unsigned)a0);
        unsigned long long k1 = ((unsigned long long)__float_as_uint(v1) << 32)
                              | (unsigned)(0xFFFFFFFFu - (unsigned)a1);
        unsigned long long k = (k0 > k1) ? k0 : k1;
        for (int o = 32; o > 0; o >>= 1) {
            unsigned long long other = __shfl_xor(k, o);
            if (other > k) k = other;
        }
        if (ln == 0) ks[wv] = k;
        __syncthreads();
        unsigned long long kk = ks[0];
        if (ks[1] > kk) kk = ks[1];
        if (ks[2] > kk) kk = ks[2];
        if (ks[3] > kk) kk = ks[3];
        int wa = (int)(0xFFFFFFFFu - (unsigned)(kk & 0xFFFFFFFFu));
        if (wa == a0) { m0 = true; v0 = 0.f; }
        if (wa == a1) { m1 = true; v1 = 0.f; }
        __syncthreads();
    }

    float f0 = fc_b[a0], f1 = fc_b[a1e];
    #pragma unroll 8
    for (int c = 0; c < 64; ++c) {
        float zc = z[c];
        f0 = fmaf(zc, fwT[c * 500 + a0],  f0);
        f1 = fmaf(zc, fwT[c * 500 + a1e], f1);
    }
    if (a1 >= NOUT) f1 = -1e30f;

    float mx = fmaxf(f0, f1);
    for (int o = 32; o > 0; o >>= 1) mx = fmaxf(mx, __shfl_xor(mx, o));
    if (ln == 0) rs[wv] = mx;
    __syncthreads();
    mx = fmaxf(fmaxf(rs[0], rs[1]), fmaxf(rs[2], rs[3]));
    __syncthreads();

    float e0 = expf(f0 - mx);
    float e1 = (a1 < NOUT) ? expf(f1 - mx) : 0.f;
    float sm = e0 + e1;
    for (int o = 32; o > 0; o >>= 1) sm += __shfl_xor(sm, o);
    if (ln == 0) rs[wv] = sm;
    __syncthreads();
    float Z = rs[0] + rs[1] + rs[2] + rs[3];
    __syncthreads();

    float p0 = m0 ? (e0 / Z) : 0.f;
    float p1 = m1 ? (e1 / Z) : 0.f;
    float S = p0 + p1;
    for (int o = 32; o > 0; o >>= 1) S += __shfl_xor(S, o);
    if (ln == 0) rs[wv] = S;
    __syncthreads();
    S = rs[0] + rs[1] + rs[2] + rs[3];
    __syncthreads();

    float w0 = p0 / (S + 1e-8f);
    float w1 = p1 / (S + 1e-8f);

    for (int it = 0; it < 17; ++it) {
        float c0 = fminf(fmaxf(w0, 0.f), UBV);
        float c1 = fminf(fmaxf(w1, 0.f), UBV);
        float lo = (w0 - c0) + (w1 - c1);
        float ns = ((c0 != UBV) ? c0 : 0.f) + ((c1 != UBV) ? c1 : 0.f);
        for (int o = 32; o > 0; o >>= 1) {
            lo += __shfl_xor(lo, o);
            ns += __shfl_xor(ns, o);
        }
        if (ln == 0) { rs[wv * 2] = lo; rs[wv * 2 + 1] = ns; }
        __syncthreads();
        lo = rs[0] + rs[2] + rs[4] + rs[6];
        ns = rs[1] + rs[3] + rs[5] + rs[7];
        __syncthreads();
        if (ns == 0.f) ns = 1.f;
        w0 = (c0 != UBV) ? c0 + lo * c0 / ns : c0;
        w1 = (c1 != UBV) ? c1 + lo * c1 / ns : c1;
    }

    out[(size_t)b * 500 + a0] = w0;
    if (a1 < NOUT) out[(size_t)b * 500 + a1] = w1;
}

extern "C" void kernel_launch(void* const* d_in, const int* in_sizes, int n_in,
                              void* d_out, int out_size, void* d_ws, size_t ws_size,
                              hipStream_t stream)
{
    const float* x   = (const float*)d_in[0];
    const float* c1w = (const float*)d_in[1];
    const float* c1b = (const float*)d_in[2];
    const float* c2w = (const float*)d_in[3];
    const float* c2b = (const float*)d_in[4];
    const float* pw  = (const float*)d_in[5];
    const float* pb  = (const float*)d_in[6];
    const float* aw  = (const float*)d_in[7];
    const float* ab  = (const float*)d_in[8];
    const float* fw  = (const float*)d_in[9];
    const float* fb  = (const float*)d_in[10];

    float* ws  = (float*)d_ws;
    float* out = (float*)d_out;

    (void)hipFuncSetAttribute((const void*)conv_kernel,
                              hipFuncAttributeMaxDynamicSharedMemorySize,
                              LDS_BYTES);

    prep_kernel<<<128, 256, 0, stream>>>(c1w, c2w, aw, fw, ws);
    conv_kernel<<<2048, 256, LDS_BYTES, stream>>>(x, ws, c1b, c2b, ws + OFF_POOLED);
    head_kernel<<<2048, 256, 0, stream>>>(ws, pw, pb, ab, fb, out);
}